// Round 8
// baseline (365.013 us; speedup 1.0000x reference)
//
#include <hip/hip_runtime.h>

// ---------------------------------------------------------------------------
// GraphSAGE x3 (sum aggr) + global mean pool.
// bf16 storage + MFMA 16x16x32 GEMMs (fp32 accum).
// Fused per layer: [gather-aggregate -> LDS] + [MFMA GEMM] in one kernel so
// gather (memory pipe) overlaps MFMA (matrix pipe) across blocks.
// ---------------------------------------------------------------------------

typedef unsigned short u16;
typedef __attribute__((ext_vector_type(8))) short bf16x8;
typedef __attribute__((ext_vector_type(4))) float f32x4;

__device__ __forceinline__ u16 f2b(float f) {
    union { float f; unsigned u; } v; v.f = f;
    unsigned u = v.u;
    return (u16)((u + 0x7FFF + ((u >> 16) & 1)) >> 16);   // RNE
}
__device__ __forceinline__ float b2f(u16 h) {
    union { unsigned u; float f; } v; v.u = ((unsigned)h) << 16;
    return v.f;
}
__device__ __forceinline__ float blo(unsigned u) {
    union { unsigned u; float f; } v; v.u = u << 16;
    return v.f;
}
__device__ __forceinline__ float bhi(unsigned u) {
    union { unsigned u; float f; } v; v.u = u & 0xffff0000u;
    return v.f;
}

// ---------------- prep: x -> bf16, weights -> bf16 transposed [D][KP] ----------------
__global__ void k_prep(const float* __restrict__ x,
                       const float* __restrict__ W1l, const float* __restrict__ W1r,
                       const float* __restrict__ W2l, const float* __restrict__ W2r,
                       const float* __restrict__ W3l, const float* __restrict__ W3r,
                       u16* __restrict__ xb,
                       u16* __restrict__ wt1l, u16* __restrict__ wt1r,
                       u16* __restrict__ wt2l, u16* __restrict__ wt2r,
                       u16* __restrict__ wt3l, u16* __restrict__ wt3r, int N) {
    long idx = (long)blockIdx.x * 256 + threadIdx.x;
    long s0 = (long)N * 54;
    if (idx < s0) { xb[idx] = f2b(x[idx]); return; }
    idx -= s0;
    if (idx < 2 * 128 * 64) {
        u16* o = (idx < 128 * 64) ? wt1l : wt1r;
        const float* w = (idx < 128 * 64) ? W1l : W1r;
        long loc = idx % (128 * 64);
        int d = (int)(loc >> 6), k = (int)(loc & 63);
        o[loc] = (k < 54) ? f2b(w[(long)k * 128 + d]) : 0;
        return;
    }
    idx -= 2 * 128 * 64;
    if (idx < 2 * 256 * 128) {
        u16* o = (idx < 256 * 128) ? wt2l : wt2r;
        const float* w = (idx < 256 * 128) ? W2l : W2r;
        long loc = idx % (256 * 128);
        int d = (int)(loc >> 7), k = (int)(loc & 127);
        o[loc] = f2b(w[(long)k * 256 + d]);
        return;
    }
    idx -= 2 * 256 * 128;
    if (idx < 2 * 256 * 256) {
        u16* o = (idx < 256 * 256) ? wt3l : wt3r;
        const float* w = (idx < 256 * 256) ? W3l : W3r;
        long loc = idx % (256 * 256);
        int d = (int)(loc >> 8), k = (int)(loc & 255);
        o[loc] = f2b(w[(long)k * 256 + d]);
    }
}

// ---------------- CSR build ----------------
__global__ void k_count(const int* __restrict__ dst, int* __restrict__ cnt, int E) {
    int e = blockIdx.x * 256 + threadIdx.x;
    if (e < E) atomicAdd(&cnt[dst[e]], 1);
}

__global__ void k_bsum(const int* __restrict__ cnt, int* __restrict__ bsum, int N) {
    __shared__ int sm[256];
    int i = blockIdx.x * 256 + threadIdx.x;
    sm[threadIdx.x] = (i < N) ? cnt[i] : 0;
    __syncthreads();
    for (int off = 128; off > 0; off >>= 1) {
        if (threadIdx.x < off) sm[threadIdx.x] += sm[threadIdx.x + off];
        __syncthreads();
    }
    if (threadIdx.x == 0) bsum[blockIdx.x] = sm[0];
}

__global__ void k_bscan(const int* __restrict__ bsum, int* __restrict__ boff, int NB) {
    __shared__ int sm[256];
    int t = threadIdx.x;
    int v = (t < NB) ? bsum[t] : 0;
    sm[t] = v;
    __syncthreads();
    for (int off = 1; off < 256; off <<= 1) {
        int add = (t >= off) ? sm[t - off] : 0;
        __syncthreads();
        sm[t] += add;
        __syncthreads();
    }
    if (t < NB) boff[t] = sm[t] - v;  // exclusive
}

__global__ void k_scan(const int* __restrict__ cnt, const int* __restrict__ boff,
                       int* __restrict__ rowptr, int* __restrict__ wpos, int N, int E) {
    __shared__ int sm[256];
    int t = threadIdx.x;
    int i = blockIdx.x * 256 + t;
    int v = (i < N) ? cnt[i] : 0;
    sm[t] = v;
    __syncthreads();
    for (int off = 1; off < 256; off <<= 1) {
        int add = (t >= off) ? sm[t - off] : 0;
        __syncthreads();
        sm[t] += add;
        __syncthreads();
    }
    int ex = sm[t] - v + boff[blockIdx.x];
    if (i < N) { rowptr[i] = ex; wpos[i] = ex; }
    if (i == 0) rowptr[N] = E;
}

__global__ void k_fill(const int* __restrict__ src, const int* __restrict__ dst,
                       int* __restrict__ wpos, int* __restrict__ csr, int E) {
    int e = blockIdx.x * 256 + threadIdx.x;
    if (e < E) {
        int p = atomicAdd(&wpos[dst[e]], 1);
        csr[p] = src[e];
    }
}

// ---------------- fused layer: agg (gather) + MFMA GEMM ----------------
// C = relu(agg(h)@Wl + h@Wr + bias); h: [N][KA] bf16, Wt*: [DOUT][KW] bf16
// (transposed, k-padded). 512 threads = 8 waves; BM=64 nodes per block.
// Phase 1: each wave gathers+aggregates 8 nodes into LDS aggL (fp32 accum).
// Phase 2: MFMA; A1-frags from aggL, A2-frags direct from global (L2-hit),
// W staged in LDS per k-tile. Wave grid 2x4: per-wave 32 rows x DOUT/4 cols.
template <int KA, int KW, int DOUT, int EPW>
__global__ __launch_bounds__(512) void k_fused(const u16* __restrict__ h,
                                               const int* __restrict__ rowptr,
                                               const int* __restrict__ csr,
                                               const u16* __restrict__ Wt1,
                                               const u16* __restrict__ Wt2,
                                               const float* __restrict__ bias,
                                               u16* __restrict__ C, int N) {
    constexpr int KAP = KW + 8;            // row stride: (KW+8)/2 words == 4 mod 32
    constexpr int WCOL = DOUT / 4;         // columns per wave (4 col-waves)
    constexpr int FN = WCOL / 16;          // 16-wide col frags per wave
    __shared__ u16 aggL[64 * KAP];
    __shared__ u16 xL[(KA == 54) ? 64 * KAP : 8];   // layer-1 only: padded x rows
    __shared__ u16 Bs[DOUT * 40];

    const int tid = threadIdx.x;
    const int w = tid >> 6, lane = tid & 63;
    const int m0 = blockIdx.x * 64;

    // ---------------- phase 1: gather + aggregate 8 nodes per wave ----------------
    for (int t = 0; t < 8; ++t) {
        int r = w * 8 + t;                 // local row 0..63
        int node = m0 + r;
        if constexpr (KA == 54) {
            // scalar gather, lanes 0..53; also stage padded x row
            u16 xv = 0;
            if (node < N && lane < 54) xv = h[(size_t)node * 54 + lane];
            xL[r * KAP + lane] = xv;       // zero pad 54..63
            float a = 0.f;
            if (node < N && lane < 54) {
                int b0 = rowptr[node], b1 = rowptr[node + 1];
                #pragma unroll 8
                for (int b = b0; b < b1; ++b)
                    a += b2f(h[(size_t)csr[b] * 54 + lane]);
            }
            aggL[r * KAP + lane] = f2b(a);
        } else {
            constexpr int GRP = 64 / EPW;  // lanes per edge; KA == GRP*8
            static_assert(KA == GRP * 8, "geometry");
            int sub = lane / GRP, dl = lane % GRP;
            float a0 = 0.f, a1 = 0.f, a2 = 0.f, a3 = 0.f;
            float a4 = 0.f, a5 = 0.f, a6 = 0.f, a7 = 0.f;
            if (node < N) {
                int b0 = rowptr[node], b1 = rowptr[node + 1];
                int b = b0;
                #pragma unroll 4
                for (; b + EPW <= b1; b += EPW) {
                    int s = csr[b + sub];
                    uint4 v = *reinterpret_cast<const uint4*>(h + (size_t)s * KA + dl * 8);
                    a0 += blo(v.x); a1 += bhi(v.x);
                    a2 += blo(v.y); a3 += bhi(v.y);
                    a4 += blo(v.z); a5 += bhi(v.z);
                    a6 += blo(v.w); a7 += bhi(v.w);
                }
                int rem = b1 - b;
                if (sub < rem) {
                    int s = csr[b + sub];
                    uint4 v = *reinterpret_cast<const uint4*>(h + (size_t)s * KA + dl * 8);
                    a0 += blo(v.x); a1 += bhi(v.x);
                    a2 += blo(v.y); a3 += bhi(v.y);
                    a4 += blo(v.z); a5 += bhi(v.z);
                    a6 += blo(v.w); a7 += bhi(v.w);
                }
            }
            #pragma unroll
            for (int off = GRP; off < 64; off <<= 1) {
                a0 += __shfl_xor(a0, off, 64);
                a1 += __shfl_xor(a1, off, 64);
                a2 += __shfl_xor(a2, off, 64);
                a3 += __shfl_xor(a3, off, 64);
                a4 += __shfl_xor(a4, off, 64);
                a5 += __shfl_xor(a5, off, 64);
                a6 += __shfl_xor(a6, off, 64);
                a7 += __shfl_xor(a7, off, 64);
            }
            if (sub == 0) {
                uint4 o;
                o.x = ((unsigned)f2b(a0)) | (((unsigned)f2b(a1)) << 16);
                o.y = ((unsigned)f2b(a2)) | (((unsigned)f2b(a3)) << 16);
                o.z = ((unsigned)f2b(a4)) | (((unsigned)f2b(a5)) << 16);
                o.w = ((unsigned)f2b(a6)) | (((unsigned)f2b(a7)) << 16);
                *reinterpret_cast<uint4*>(&aggL[r * KAP + dl * 8]) = o;
            }
        }
    }
    __syncthreads();

    // ---------------- phase 2: MFMA GEMM ----------------
    const int wr = w >> 2, wc = w & 3;     // 2x4 wave grid
    const int lo = lane & 15, hi = lane >> 4;

    f32x4 acc[2][FN];
    #pragma unroll
    for (int i = 0; i < 2; ++i)
        #pragma unroll
        for (int j = 0; j < FN; ++j) acc[i][j] = {0.f, 0.f, 0.f, 0.f};

    constexpr int KT = KW / 32;

    #pragma unroll
    for (int s = 0; s < 2; ++s) {
        const u16* __restrict__ Wp = s ? Wt2 : Wt1;
        for (int kt = 0; kt < KT; ++kt) {
            const int k0 = kt * 32;
            // stage W tile [DOUT][32] (row pad 40)
            #pragma unroll
            for (int it = 0; it < DOUT / 128; ++it) {
                int v = it * 512 + tid;
                int r = v >> 2, c = v & 3;
                uint4 val = *reinterpret_cast<const uint4*>(Wp + (size_t)r * KW + k0 + c * 8);
                *reinterpret_cast<uint4*>(&Bs[r * 40 + c * 8]) = val;
            }
            __syncthreads();
            // A-frags (rows of this wave)
            bf16x8 bfr[2];
            if (s == 0) {
                #pragma unroll
                for (int fm = 0; fm < 2; ++fm)
                    bfr[fm] = *reinterpret_cast<const bf16x8*>(&aggL[(wr * 32 + fm * 16 + lo) * KAP + k0 + hi * 8]);
            } else if constexpr (KA == 54) {
                #pragma unroll
                for (int fm = 0; fm < 2; ++fm)
                    bfr[fm] = *reinterpret_cast<const bf16x8*>(&xL[(wr * 32 + fm * 16 + lo) * KAP + k0 + hi * 8]);
            } else {
                #pragma unroll
                for (int fm = 0; fm < 2; ++fm) {
                    int m = m0 + wr * 32 + fm * 16 + lo;
                    bf16x8 z = {0, 0, 0, 0, 0, 0, 0, 0};
                    bfr[fm] = (m < N) ? *reinterpret_cast<const bf16x8*>(h + (size_t)m * KA + k0 + hi * 8) : z;
                }
            }
            #pragma unroll
            for (int fn = 0; fn < FN; ++fn) {
                bf16x8 af = *reinterpret_cast<const bf16x8*>(&Bs[(wc * WCOL + fn * 16 + lo) * 40 + hi * 8]);
                #pragma unroll
                for (int fm = 0; fm < 2; ++fm)
                    acc[fm][fn] = __builtin_amdgcn_mfma_f32_16x16x32_bf16(af, bfr[fm], acc[fm][fn], 0, 0, 0);
            }
            __syncthreads();
        }
    }
    // epilogue: D[feat][node]; feat = wc*WCOL + fn*16 + hi*4 + j, node = wr*32+fm*16+lo
    #pragma unroll
    for (int fm = 0; fm < 2; ++fm) {
        int node = m0 + wr * 32 + fm * 16 + lo;
        if (node < N) {
            #pragma unroll
            for (int fn = 0; fn < FN; ++fn) {
                int fb = wc * WCOL + fn * 16 + hi * 4;
                float4 bv = *reinterpret_cast<const float4*>(bias + fb);
                ushort4 o;
                o.x = f2b(fmaxf(acc[fm][fn][0] + bv.x, 0.f));
                o.y = f2b(fmaxf(acc[fm][fn][1] + bv.y, 0.f));
                o.z = f2b(fmaxf(acc[fm][fn][2] + bv.z, 0.f));
                o.w = f2b(fmaxf(acc[fm][fn][3] + bv.w, 0.f));
                *reinterpret_cast<ushort4*>(C + (size_t)node * DOUT + fb) = o;
            }
        }
    }
}

// ---------------- global mean pool (bf16 in, fp32 out) ----------------
template <int ROWS>
__global__ void k_pool(const u16* __restrict__ h3, const int* __restrict__ batch,
                       float* __restrict__ outsum, int* __restrict__ cnt, int N) {
    int r0 = blockIdx.x * ROWS;
    int r1 = min(r0 + ROWS, N);
    if (r0 >= N) return;
    int d = threadIdx.x;
    int cur = batch[r0];
    float s = 0.f;
    int c = 0;
    for (int i = r0; i < r1; ++i) {
        int g = batch[i];  // uniform across block
        if (g != cur) {
            atomicAdd(&outsum[cur * 256 + d], s);
            if (d == 0) atomicAdd(&cnt[cur], c);
            s = 0.f; c = 0; cur = g;
        }
        s += b2f(h3[(size_t)i * 256 + d]);
        c++;
    }
    atomicAdd(&outsum[cur * 256 + d], s);
    if (d == 0) atomicAdd(&cnt[cur], c);
}

__global__ void k_div(float* __restrict__ out, const int* __restrict__ cnt, int total) {
    int idx = blockIdx.x * 256 + threadIdx.x;
    if (idx < total) {
        float c = fmaxf((float)cnt[idx >> 8], 1.0f);
        out[idx] = out[idx] / c;
    }
}

// ---------------------------------------------------------------------------
extern "C" void kernel_launch(void* const* d_in, const int* in_sizes, int n_in,
                              void* d_out, int out_size, void* d_ws, size_t ws_size,
                              hipStream_t stream) {
    const float* x   = (const float*)d_in[0];
    const int* ei    = (const int*)d_in[1];
    const int* batch = (const int*)d_in[2];
    const float* W1l = (const float*)d_in[3];
    const float* b1  = (const float*)d_in[4];
    const float* W1r = (const float*)d_in[5];
    const float* W2l = (const float*)d_in[6];
    const float* b2  = (const float*)d_in[7];
    const float* W2r = (const float*)d_in[8];
    const float* W3l = (const float*)d_in[9];
    const float* b3  = (const float*)d_in[10];
    const float* W3r = (const float*)d_in[11];

    const int N = in_sizes[0] / 54;
    const int E = in_sizes[1] / 2;
    const int* src = ei;
    const int* dst = ei + E;

    // workspace layout (bf16 = u16)
    u16* xb   = (u16*)d_ws;                       // N*54
    u16* buf1 = xb + (size_t)N * 54;              // h1 / h3
    u16* buf2 = buf1 + (size_t)N * 256;           // h2
    u16* wt1l = buf2 + (size_t)N * 256;           // [128][64]
    u16* wt1r = wt1l + 128 * 64;
    u16* wt2l = wt1r + 128 * 64;                  // [256][128]
    u16* wt2r = wt2l + 256 * 128;
    u16* wt3l = wt2r + 256 * 128;                 // [256][256]
    u16* wt3r = wt3l + 256 * 256;
    int* ip = (int*)(wt3r + 256 * 256);
    int* cntdeg  = ip; ip += N;
    int* rowptr  = ip; ip += N + 1;
    int* wpos    = ip; ip += N + 1;
    int* bsum    = ip; ip += 256;
    int* boff    = ip; ip += 256;
    int* cntpool = ip; ip += 128;
    int* csr     = ip;                            // E ints

    hipMemsetAsync(cntdeg, 0, (size_t)N * sizeof(int), stream);
    hipMemsetAsync(d_out, 0, (size_t)out_size * sizeof(float), stream);
    hipMemsetAsync(cntpool, 0, 128 * sizeof(int), stream);

    const int NB = (N + 255) / 256;
    const int EB = (E + 255) / 256;

    // prep: bf16 conversions + weight transposes
    {
        long total = (long)N * 54 + 2L * 128 * 64 + 2L * 256 * 128 + 2L * 256 * 256;
        int g = (int)((total + 255) / 256);
        k_prep<<<g, 256, 0, stream>>>(x, W1l, W1r, W2l, W2r, W3l, W3r,
                                      xb, wt1l, wt1r, wt2l, wt2r, wt3l, wt3r, N);
    }

    // CSR build
    k_count<<<EB, 256, 0, stream>>>(dst, cntdeg, E);
    k_bsum<<<NB, 256, 0, stream>>>(cntdeg, bsum, N);
    k_bscan<<<1, 256, 0, stream>>>(bsum, boff, NB);
    k_scan<<<NB, 256, 0, stream>>>(cntdeg, boff, rowptr, wpos, N, E);
    k_fill<<<EB, 256, 0, stream>>>(src, dst, wpos, csr, E);

    const int GB = (N + 63) / 64;

    // layer 1: 54 -> 128
    k_fused<54, 64, 128, 1><<<GB, 512, 0, stream>>>(xb, rowptr, csr, wt1l, wt1r, b1, buf1, N);
    // layer 2: 128 -> 256
    k_fused<128, 128, 256, 4><<<GB, 512, 0, stream>>>(buf1, rowptr, csr, wt2l, wt2r, b2, buf2, N);
    // layer 3: 256 -> 256
    k_fused<256, 256, 256, 2><<<GB, 512, 0, stream>>>(buf2, rowptr, csr, wt3l, wt3r, b3, buf1, N);

    // global mean pool
    k_pool<32><<<(N + 31) / 32, 256, 0, stream>>>(buf1, batch, (float*)d_out, cntpool, N);
    k_div<<<(out_size + 255) / 256, 256, 0, stream>>>((float*)d_out, cntpool, out_size);
}